// Round 2
// baseline (1189.325 us; speedup 1.0000x reference)
//
#include <hip/hip_runtime.h>
#include <math.h>

#define T_STEPS 19
#define V 50257
#define EMB 300
#define HDIM 512
#define NP 256
#define ML 50
#define CIN 812
#define NEGV -1e9f
#define NBLK 128   // blocks in the persistent recurrence kernel

// ---- workspace layout (float indices) ----
#define OFF_X      0                         // 19*300 = 5700
#define OFF_POP    5700                      // 19*256
#define OFF_PL     10564                     // 19*256
#define OFF_PC     15428                     // 19*512
#define OFF_HS     25156                     // 20*512 (Hs[0]=input hidden)
#define OFF_H1OP   35396                     // 256
#define OFF_H1L    35652                     // 256
#define OFF_GH     35908                     // 1536
#define OFF_C1     37444                     // 512
#define OFF_G      37956                     // 512
#define OFF_LOGOP  38468                     // 256
#define OFF_LOGL   38724                     // 64
#define OFF_MPROP  38788                     // 512*256 = 131072
#define OFF_MENC   169860                    // 512*50  = 25600
#define OFF_BAR    195460                    // barrier counters (uints), 64 floats

// ---- output layout (floats) ----
#define OUT_LOGITS 0
#define OUT_ATTW   ((long)T_STEPS * V)
#define OUT_ATTOB  (OUT_ATTW + (long)T_STEPS * ML)

__device__ __forceinline__ float wred(float v) {
  v += __shfl_xor(v, 32, 64);
  v += __shfl_xor(v, 16, 64);
  v += __shfl_xor(v, 8, 64);
  v += __shfl_xor(v, 4, 64);
  v += __shfl_xor(v, 2, 64);
  v += __shfl_xor(v, 1, 64);
  return v;
}

__device__ __forceinline__ float dot4(float4 a, float4 b) {
  return a.x * b.x + a.y * b.y + a.z * b.z + a.w * b.w;
}

// device-scope generation barrier (all NBLK blocks co-resident by construction)
__device__ __forceinline__ void gbar(unsigned* cnt, unsigned* gen) {
  __syncthreads();
  if (threadIdx.x == 0) {
    __threadfence();  // release prior writes to agent scope
    unsigned g = __hip_atomic_load(gen, __ATOMIC_RELAXED, __HIP_MEMORY_SCOPE_AGENT);
    unsigned a = __hip_atomic_fetch_add(cnt, 1u, __ATOMIC_ACQ_REL, __HIP_MEMORY_SCOPE_AGENT);
    if (a == (unsigned)(NBLK - 1)) {
      __hip_atomic_store(cnt, 0u, __ATOMIC_RELAXED, __HIP_MEMORY_SCOPE_AGENT);
      __hip_atomic_fetch_add(gen, 1u, __ATOMIC_ACQ_REL, __HIP_MEMORY_SCOPE_AGENT);
    } else {
      while (__hip_atomic_load(gen, __ATOMIC_ACQUIRE, __HIP_MEMORY_SCOPE_AGENT) == g) {
        __builtin_amdgcn_s_sleep(2);
      }
    }
    __threadfence();  // acquire side
  }
  __syncthreads();
}

// Precompute X = relu(emb[token]) for all steps; copy Hs[0].
__global__ void k_pre1(const int* __restrict__ tok0, const int* __restrict__ ans,
                       const float* __restrict__ emb, const float* __restrict__ hidden,
                       float* __restrict__ ws) {
  int tid = blockIdx.x * 256 + threadIdx.x;
  if (tid < T_STEPS * EMB) {
    int s = tid / EMB, j = tid - s * EMB;
    int t = (s == 0) ? tok0[0] : ans[s];
    float v = emb[(long)t * EMB + j];
    ws[OFF_X + tid] = v > 0.f ? v : 0.f;
  } else {
    int k = tid - T_STEPS * EMB;
    if (k < HDIM) ws[OFF_HS + k] = hidden[k];
  }
}

// P_op/P_l/P_c: x-column partials + layer-1 biases. wave-per-row, 19*1024 rows.
__global__ void k_pre2(const float* __restrict__ w1op, const float* __restrict__ b1op,
                       const float* __restrict__ w1l,  const float* __restrict__ b1l,
                       const float* __restrict__ wc1,  const float* __restrict__ bc1,
                       float* __restrict__ ws) {
  int gw = (blockIdx.x * 256 + threadIdx.x) >> 6;
  int lane = threadIdx.x & 63;
  int s = gw >> 10;
  int rr = gw & 1023;
  if (s >= T_STEPS) return;
  const float* wrow; const float* bias; float* dst; int r;
  if (rr < 256)      { r = rr;       wrow = w1op + (long)r * CIN; bias = b1op; dst = ws + OFF_POP + s * 256 + r; }
  else if (rr < 512) { r = rr - 256; wrow = w1l  + (long)r * CIN; bias = b1l;  dst = ws + OFF_PL  + s * 256 + r; }
  else               { r = rr - 512; wrow = wc1  + (long)r * CIN; bias = bc1;  dst = ws + OFF_PC  + s * 512 + r; }
  const float* x = ws + OFF_X + s * EMB;
  float acc = 0.f;
#pragma unroll
  for (int it = 0; it < 5; ++it) {
    int j = it * 64 + lane;
    if (j < EMB) acc += wrow[j] * x[j];
  }
  acc = wred(acc);
  if (lane == 0) *dst = acc + bias[r];
}

// M_prop[r][p] = sum_k cmb_w1[r][556+k]*prop[p][k]; M_enc[r][j] = sum_k cmb_w1[r][300+k]*enc[j][k]
#define LDSF 12850
__global__ void __launch_bounds__(256) k_mprep(const float* __restrict__ cw1,
                                               const float* __restrict__ prop,
                                               const float* __restrict__ enc,
                                               float* __restrict__ ws) {
  __shared__ float lds[LDSF];
  int tid = threadIdx.x, r = blockIdx.x;
  float acc = 0.f;
  for (int kc = 0; kc < 8; ++kc) {
    __syncthreads();
    // stage prop[:, kc*32 .. +32] -> lds [256][33]
#pragma unroll
    for (int i = 0; i < 8; ++i) {
      int f = tid + 256 * i; int row = f >> 3, q = f & 7;
      float4 v = *(const float4*)(prop + (long)row * 256 + kc * 32 + 4 * q);
      float* p = lds + row * 33 + 4 * q;
      p[0] = v.x; p[1] = v.y; p[2] = v.z; p[3] = v.w;
    }
    __syncthreads();
    const float* wbase = cw1 + (long)r * CIN + 556 + kc * 32;
    const float* pl = lds + tid * 33;
#pragma unroll
    for (int k4 = 0; k4 < 8; ++k4) {
      float4 w4 = *(const float4*)(wbase + 4 * k4);
      const float* pp = pl + 4 * k4;
      acc += w4.x * pp[0] + w4.y * pp[1] + w4.z * pp[2] + w4.w * pp[3];
    }
  }
  ws[OFF_MPROP + (long)r * 256 + tid] = acc;
  // enc part: stage all of enc [50][256] -> lds [50][257]
  __syncthreads();
  for (int i = 0; i < 13; ++i) {
    int f = tid + 256 * i;
    if (f < 3200) {
      int row = f >> 6, q = f & 63;
      float4 v = *(const float4*)(enc + (long)row * 256 + 4 * q);
      float* p = lds + row * 257 + 4 * q;
      p[0] = v.x; p[1] = v.y; p[2] = v.z; p[3] = v.w;
    }
  }
  __syncthreads();
  if (tid < ML) {
    const float* wb2 = cw1 + (long)r * CIN + 300;
    const float* el = lds + tid * 257;
    float a2 = 0.f;
#pragma unroll 8
    for (int k = 0; k < 256; ++k) a2 += wb2[k] * el[k];
    ws[OFF_MENC + (long)r * ML + tid] = a2;
  }
}

// Persistent fused recurrence: 19 steps x 5 phases, device barrier between phases.
__global__ void __launch_bounds__(256) k_recur(
    const float* __restrict__ w1op, const float* __restrict__ w1l,
    const float* __restrict__ whh,  const float* __restrict__ bhh,
    const float* __restrict__ w2op, const float* __restrict__ b2op,
    const float* __restrict__ w2l,  const float* __restrict__ b2l,
    const int* __restrict__ obj_mask, const int* __restrict__ lang_mask,
    const float* __restrict__ wc2,  const float* __restrict__ bc2,
    const float* __restrict__ wih,  const float* __restrict__ bih,
    float* ws, float* __restrict__ out) {
  const int tid = threadIdx.x;
  const int lane = tid & 63;
  const int wv = (blockIdx.x << 2) + (tid >> 6);   // 0..511
  unsigned* cnt = (unsigned*)(ws + OFF_BAR);
  unsigned* gen = (unsigned*)(ws + OFF_BAR + 32);
  __shared__ float red[256];
  __shared__ __align__(16) float sm_aop[256];
  __shared__ float sm_al[64];

  for (int s = 0; s < T_STEPS; ++s) {
    // ---------- Phase A: h1op(256) | h1l(256) + gh(1536) ----------
    {
      const float* h = ws + OFF_HS + s * HDIM;
      float4 ha = *(const float4*)(h + 4 * lane);
      float4 hb = *(const float4*)(h + 256 + 4 * lane);
      const float* w0 = (wv < 256) ? (w1op + (long)wv * CIN + 300)
                                   : (w1l + (long)(wv - 256) * CIN + 300);
      const float* w1r = whh + (long)wv * HDIM;
      const float* w2r = whh + (long)(wv + 512) * HDIM;
      const float* w3r = whh + (long)(wv + 1024) * HDIM;
      float a0 = dot4(*(const float4*)(w0 + 4 * lane), ha) + dot4(*(const float4*)(w0 + 256 + 4 * lane), hb);
      float a1 = dot4(*(const float4*)(w1r + 4 * lane), ha) + dot4(*(const float4*)(w1r + 256 + 4 * lane), hb);
      float a2 = dot4(*(const float4*)(w2r + 4 * lane), ha) + dot4(*(const float4*)(w2r + 256 + 4 * lane), hb);
      float a3 = dot4(*(const float4*)(w3r + 4 * lane), ha) + dot4(*(const float4*)(w3r + 256 + 4 * lane), hb);
      a0 = wred(a0); a1 = wred(a1); a2 = wred(a2); a3 = wred(a3);
      if (lane == 0) {
        if (wv < 256) {
          float v = a0 + ws[OFF_POP + s * 256 + wv];
          ws[OFF_H1OP + wv] = v > 0.f ? v : 0.f;
        } else {
          float v = a0 + ws[OFF_PL + s * 256 + (wv - 256)];
          ws[OFF_H1L + (wv - 256)] = v > 0.f ? v : 0.f;
        }
        ws[OFF_GH + wv]        = a1 + bhh[wv];
        ws[OFF_GH + 512 + wv]  = a2 + bhh[512 + wv];
        ws[OFF_GH + 1024 + wv] = a3 + bhh[1024 + wv];
      }
    }
    gbar(cnt, gen);
    // ---------- Phase B: attention logits (306 rows) ----------
    if (wv < 306) {
      if (wv < 256) {
        float4 h1 = *(const float4*)(ws + OFF_H1OP + 4 * lane);
        const float* wr = w2op + (long)wv * 256;
        float acc = wred(dot4(*(const float4*)(wr + 4 * lane), h1));
        if (lane == 0) ws[OFF_LOGOP + wv] = acc + b2op[wv];
      } else {
        int r = wv - 256;
        float4 h1 = *(const float4*)(ws + OFF_H1L + 4 * lane);
        const float* wr = w2l + (long)r * 256;
        float acc = wred(dot4(*(const float4*)(wr + 4 * lane), h1));
        if (lane == 0) ws[OFF_LOGL + r] = acc + b2l[r];
      }
    }
    gbar(cnt, gen);
    // ---------- Phase C: block-redundant softmax + c1 ----------
    {
      float vo = (obj_mask[tid] != 0) ? NEGV : ws[OFF_LOGOP + tid];
      red[tid] = vo; __syncthreads();
      for (int st = 128; st > 0; st >>= 1) { if (tid < st) red[tid] = fmaxf(red[tid], red[tid + st]); __syncthreads(); }
      float mo = red[0]; __syncthreads();
      float eo = expf(vo - mo);
      red[tid] = eo; __syncthreads();
      for (int st = 128; st > 0; st >>= 1) { if (tid < st) red[tid] += red[tid + st]; __syncthreads(); }
      float aop = eo / red[0];
      sm_aop[tid] = aop;
      __syncthreads();
      float vl = (tid < ML) ? ((lang_mask[tid] != 0) ? NEGV : ws[OFF_LOGL + tid]) : -3e38f;
      red[tid] = vl; __syncthreads();
      for (int st = 128; st > 0; st >>= 1) { if (tid < st) red[tid] = fmaxf(red[tid], red[tid + st]); __syncthreads(); }
      float ml_ = red[0]; __syncthreads();
      float el = (tid < ML) ? expf(vl - ml_) : 0.f;
      red[tid] = el; __syncthreads();
      for (int st = 128; st > 0; st >>= 1) { if (tid < st) red[tid] += red[tid + st]; __syncthreads(); }
      float al = el / red[0];
      if (tid < 64) sm_al[tid] = (tid < ML) ? al : 0.f;
      __syncthreads();
      if (blockIdx.x == 0) {
        out[OUT_ATTOB + (long)s * NP + tid] = aop;
        if (tid < ML) out[OUT_ATTW + (long)s * ML + tid] = al;
      }
      // c1 row r = wv
      int r = wv;
      const float* mp = ws + OFF_MPROP + (long)r * 256;
      float4 m4 = *(const float4*)(mp + 4 * lane);
      float4 a4 = *(const float4*)(&sm_aop[4 * lane]);
      float acc = dot4(m4, a4);
      if (lane < ML) acc += ws[OFF_MENC + (long)r * ML + lane] * sm_al[lane];
      acc = wred(acc);
      if (lane == 0) {
        float v = acc + ws[OFF_PC + s * HDIM + r];
        ws[OFF_C1 + r] = v > 0.f ? v : 0.f;
      }
    }
    gbar(cnt, gen);
    // ---------- Phase D: g = relu(Wc2 @ c1 + b2) ----------
    {
      int r = wv;
      float4 ca = *(const float4*)(ws + OFF_C1 + 4 * lane);
      float4 cb = *(const float4*)(ws + OFF_C1 + 256 + 4 * lane);
      const float* wr = wc2 + (long)r * HDIM;
      float acc = wred(dot4(*(const float4*)(wr + 4 * lane), ca) + dot4(*(const float4*)(wr + 256 + 4 * lane), cb));
      if (lane == 0) {
        float v = acc + bc2[r];
        ws[OFF_G + r] = v > 0.f ? v : 0.f;
      }
    }
    gbar(cnt, gen);
    // ---------- Phase E: GRU fuse -> h_{s+1} ----------
    {
      int j = wv;
      float4 ga = *(const float4*)(ws + OFF_G + 4 * lane);
      float4 gb = *(const float4*)(ws + OFF_G + 256 + 4 * lane);
      const float* p0 = wih + (long)j * HDIM;
      const float* p1 = wih + (long)(j + 512) * HDIM;
      const float* p2 = wih + (long)(j + 1024) * HDIM;
      float a0 = dot4(*(const float4*)(p0 + 4 * lane), ga) + dot4(*(const float4*)(p0 + 256 + 4 * lane), gb);
      float a1 = dot4(*(const float4*)(p1 + 4 * lane), ga) + dot4(*(const float4*)(p1 + 256 + 4 * lane), gb);
      float a2 = dot4(*(const float4*)(p2 + 4 * lane), ga) + dot4(*(const float4*)(p2 + 256 + 4 * lane), gb);
      a0 = wred(a0); a1 = wred(a1); a2 = wred(a2);
      if (lane == 0) {
        float ir = a0 + bih[j], iz = a1 + bih[512 + j], in_ = a2 + bih[1024 + j];
        float hr = ws[OFF_GH + j], hz = ws[OFF_GH + 512 + j], hn = ws[OFF_GH + 1024 + j];
        float rg = 1.f / (1.f + expf(-(ir + hr)));
        float zg = 1.f / (1.f + expf(-(iz + hz)));
        float ng = tanhf(in_ + rg * hn);
        float hp = ws[OFF_HS + s * HDIM + j];
        ws[OFF_HS + (s + 1) * HDIM + j] = (1.f - zg) * ng + zg * hp;
      }
    }
    gbar(cnt, gen);
  }
}

// logits: LDS-tiled GEMM. 256 rows/block, k-chunks of 32, thread-owns-row.
__global__ void __launch_bounds__(256) k_final2(const float* __restrict__ ow,
                                                const float* __restrict__ ob,
                                                const float* __restrict__ ws,
                                                float* __restrict__ out) {
  __shared__ __align__(16) float wl[256 * 36];
  __shared__ __align__(16) float hl[T_STEPS * 512];
  int tid = threadIdx.x;
  long rbase = (long)blockIdx.x * 256;
  for (int i = tid; i < T_STEPS * 512; i += 256) hl[i] = ws[OFF_HS + 512 + i];
  float4 st[8];
  // prologue load chunk 0
#pragma unroll
  for (int i = 0; i < 8; ++i) {
    int f = tid + 256 * i; int row = f >> 3, q = f & 7;
    long r = rbase + row;
    st[i] = (r < V) ? *(const float4*)(ow + r * 512 + 4 * q) : make_float4(0.f, 0.f, 0.f, 0.f);
  }
  float acc[T_STEPS];
#pragma unroll
  for (int s = 0; s < T_STEPS; ++s) acc[s] = 0.f;
  __syncthreads();  // hl ready
  for (int c = 0; c < 16; ++c) {
    // write staged regs -> LDS
#pragma unroll
    for (int i = 0; i < 8; ++i) {
      int f = tid + 256 * i; int row = f >> 3, q = f & 7;
      float* p = wl + row * 36 + 4 * q;
      p[0] = st[i].x; p[1] = st[i].y; p[2] = st[i].z; p[3] = st[i].w;
    }
    __syncthreads();  // wl ready
    if (c < 15) {
#pragma unroll
      for (int i = 0; i < 8; ++i) {
        int f = tid + 256 * i; int row = f >> 3, q = f & 7;
        long r = rbase + row;
        st[i] = (r < V) ? *(const float4*)(ow + r * 512 + (c + 1) * 32 + 4 * q) : make_float4(0.f, 0.f, 0.f, 0.f);
      }
    }
    // compute: thread owns row=tid
    const float* wp = wl + tid * 36;
#pragma unroll
    for (int kq = 0; kq < 8; ++kq) {
      float4 w4 = *(const float4*)(wp + 4 * kq);
      const float* hb = hl + c * 32 + 4 * kq;
#pragma unroll
      for (int s = 0; s < T_STEPS; ++s) {
        float4 h4 = *(const float4*)(hb + s * 512);
        acc[s] += dot4(w4, h4);
      }
    }
    __syncthreads();  // done reading wl
  }
  long r = rbase + tid;
  if (r < V) {
    float b = ob[r];
#pragma unroll
    for (int s = 0; s < T_STEPS; ++s) out[OUT_LOGITS + (long)s * V + r] = acc[s] + b;
  }
}

extern "C" void kernel_launch(void* const* d_in, const int* in_sizes, int n_in,
                              void* d_out, int out_size, void* d_ws, size_t ws_size,
                              hipStream_t stream) {
  const int*   input_tok  = (const int*)d_in[0];
  const float* hidden     = (const float*)d_in[1];
  const float* enc        = (const float*)d_in[2];
  const float* prop       = (const float*)d_in[3];
  const int*   obj_mask   = (const int*)d_in[4];
  const int*   lang_mask  = (const int*)d_in[5];
  const int*   ans        = (const int*)d_in[6];
  const float* emb        = (const float*)d_in[7];
  const float* attn_w1    = (const float*)d_in[8];
  const float* attn_b1    = (const float*)d_in[9];
  const float* attn_w2    = (const float*)d_in[10];
  const float* attn_b2    = (const float*)d_in[11];
  const float* attn_op_w1 = (const float*)d_in[12];
  const float* attn_op_b1 = (const float*)d_in[13];
  const float* attn_op_w2 = (const float*)d_in[14];
  const float* attn_op_b2 = (const float*)d_in[15];
  const float* cmb_w1     = (const float*)d_in[16];
  const float* cmb_b1     = (const float*)d_in[17];
  const float* cmb_w2     = (const float*)d_in[18];
  const float* cmb_b2     = (const float*)d_in[19];
  const float* gw_ih      = (const float*)d_in[20];
  const float* gw_hh      = (const float*)d_in[21];
  const float* gb_ih      = (const float*)d_in[22];
  const float* gb_hh      = (const float*)d_in[23];
  const float* out_w      = (const float*)d_in[24];
  const float* out_b      = (const float*)d_in[25];
  float* out = (float*)d_out;
  float* ws  = (float*)d_ws;

  // reset barrier counters
  hipMemsetAsync((char*)d_ws + (size_t)OFF_BAR * 4, 0, 256, stream);
  k_pre1<<<25, 256, 0, stream>>>(input_tok, ans, emb, hidden, ws);
  k_pre2<<<4864, 256, 0, stream>>>(attn_op_w1, attn_op_b1, attn_w1, attn_b1, cmb_w1, cmb_b1, ws);
  k_mprep<<<512, 256, 0, stream>>>(cmb_w1, prop, enc, ws);
  k_recur<<<NBLK, 256, 0, stream>>>(attn_op_w1, attn_w1, gw_hh, gb_hh,
                                    attn_op_w2, attn_op_b2, attn_w2, attn_b2,
                                    obj_mask, lang_mask, cmb_w2, cmb_b2,
                                    gw_ih, gb_ih, ws, out);
  k_final2<<<(V + 255) / 256, 256, 0, stream>>>(out_w, out_b, ws, out);
}

// Round 3
// 698.634 us; speedup vs baseline: 1.7024x; 1.7024x over previous
//
#include <hip/hip_runtime.h>
#include <math.h>

#define T_STEPS 19
#define V 50257
#define EMB 300
#define HDIM 512
#define NP 256
#define ML 50
#define CIN 812
#define NEGV -1e9f
#define NBLK 128   // blocks in the persistent recurrence kernel

// ---- workspace layout (float indices) ----
#define OFF_X      0                         // 19*300 = 5700
#define OFF_POP    5700                      // 19*256
#define OFF_PL     10564                     // 19*256
#define OFF_PC     15428                     // 19*512
#define OFF_HS     25156                     // 20*512 (Hs[0]=input hidden)
#define OFF_H1OP   35396                     // 256
#define OFF_H1L    35652                     // 256
#define OFF_GH     35908                     // 1536
#define OFF_C1     37444                     // 512
#define OFF_G      37956                     // 512
#define OFF_LOGOP  38468                     // 256
#define OFF_LOGL   38724                     // 64
#define OFF_MPROP  38788                     // 512*256 = 131072
#define OFF_MENC   169860                    // 512*50  = 25600
#define OFF_BAR    195460                    // barrier counters: root@0, gen@+32, leaves@+64+32k

// ---- output layout (floats) ----
#define OUT_LOGITS 0
#define OUT_ATTW   ((long)T_STEPS * V)
#define OUT_ATTOB  (OUT_ATTW + (long)T_STEPS * ML)

__device__ __forceinline__ float wred(float v) {
  v += __shfl_xor(v, 32, 64);
  v += __shfl_xor(v, 16, 64);
  v += __shfl_xor(v, 8, 64);
  v += __shfl_xor(v, 4, 64);
  v += __shfl_xor(v, 2, 64);
  v += __shfl_xor(v, 1, 64);
  return v;
}

__device__ __forceinline__ float dot4(float4 a, float4 b) {
  return a.x * b.x + a.y * b.y + a.z * b.z + a.w * b.w;
}

// Device-scope generation barrier. Two-level arrival tree (16 leaves x 8 blocks),
// RELAXED spin + single acquire fence. Release semantics ride on the ACQ_REL RMWs.
__device__ __forceinline__ void gbar(float* wsb) {
  __syncthreads();
  if (threadIdx.x == 0) {
    unsigned* root = (unsigned*)(wsb + OFF_BAR);
    unsigned* gen  = (unsigned*)(wsb + OFF_BAR + 32);
    unsigned* leaf = (unsigned*)(wsb + OFF_BAR + 64 + 32 * (blockIdx.x & 15));
    unsigned g = __hip_atomic_load(gen, __ATOMIC_RELAXED, __HIP_MEMORY_SCOPE_AGENT);
    unsigned a = __hip_atomic_fetch_add(leaf, 1u, __ATOMIC_ACQ_REL, __HIP_MEMORY_SCOPE_AGENT);
    if (a == (NBLK / 16 - 1)) {
      __hip_atomic_store(leaf, 0u, __ATOMIC_RELAXED, __HIP_MEMORY_SCOPE_AGENT);
      unsigned r = __hip_atomic_fetch_add(root, 1u, __ATOMIC_ACQ_REL, __HIP_MEMORY_SCOPE_AGENT);
      if (r == 15u) {
        __hip_atomic_store(root, 0u, __ATOMIC_RELAXED, __HIP_MEMORY_SCOPE_AGENT);
        __hip_atomic_fetch_add(gen, 1u, __ATOMIC_RELEASE, __HIP_MEMORY_SCOPE_AGENT);
      }
    }
    while (__hip_atomic_load(gen, __ATOMIC_RELAXED, __HIP_MEMORY_SCOPE_AGENT) == g) {
      __builtin_amdgcn_s_sleep(1);
    }
    __builtin_amdgcn_fence(__ATOMIC_ACQUIRE, "agent");
  }
  __syncthreads();
}

// Precompute X = relu(emb[token]) for all steps; copy Hs[0].
__global__ void k_pre1(const int* __restrict__ tok0, const int* __restrict__ ans,
                       const float* __restrict__ emb, const float* __restrict__ hidden,
                       float* __restrict__ ws) {
  int tid = blockIdx.x * 256 + threadIdx.x;
  if (tid < T_STEPS * EMB) {
    int s = tid / EMB, j = tid - s * EMB;
    int t = (s == 0) ? tok0[0] : ans[s];
    float v = emb[(long)t * EMB + j];
    ws[OFF_X + tid] = v > 0.f ? v : 0.f;
  } else {
    int k = tid - T_STEPS * EMB;
    if (k < HDIM) ws[OFF_HS + k] = hidden[k];
  }
}

// P_op/P_l/P_c: x-column partials + layer-1 biases. wave-per-row, 19*1024 rows.
__global__ void k_pre2(const float* __restrict__ w1op, const float* __restrict__ b1op,
                       const float* __restrict__ w1l,  const float* __restrict__ b1l,
                       const float* __restrict__ wc1,  const float* __restrict__ bc1,
                       float* __restrict__ ws) {
  int gw = (blockIdx.x * 256 + threadIdx.x) >> 6;
  int lane = threadIdx.x & 63;
  int s = gw >> 10;
  int rr = gw & 1023;
  if (s >= T_STEPS) return;
  const float* wrow; const float* bias; float* dst; int r;
  if (rr < 256)      { r = rr;       wrow = w1op + (long)r * CIN; bias = b1op; dst = ws + OFF_POP + s * 256 + r; }
  else if (rr < 512) { r = rr - 256; wrow = w1l  + (long)r * CIN; bias = b1l;  dst = ws + OFF_PL  + s * 256 + r; }
  else               { r = rr - 512; wrow = wc1  + (long)r * CIN; bias = bc1;  dst = ws + OFF_PC  + s * 512 + r; }
  const float* x = ws + OFF_X + s * EMB;
  float acc = 0.f;
#pragma unroll
  for (int it = 0; it < 5; ++it) {
    int j = it * 64 + lane;
    if (j < EMB) acc += wrow[j] * x[j];
  }
  acc = wred(acc);
  if (lane == 0) *dst = acc + bias[r];
}

// M_prop[r][p] = sum_k cmb_w1[r][556+k]*prop[p][k]; M_enc[r][j] = sum_k cmb_w1[r][300+k]*enc[j][k]
#define LDSF 12850
__global__ void __launch_bounds__(256) k_mprep(const float* __restrict__ cw1,
                                               const float* __restrict__ prop,
                                               const float* __restrict__ enc,
                                               float* __restrict__ ws) {
  __shared__ float lds[LDSF];
  int tid = threadIdx.x, r = blockIdx.x;
  float acc = 0.f;
  for (int kc = 0; kc < 8; ++kc) {
    __syncthreads();
    // stage prop[:, kc*32 .. +32] -> lds [256][33]
#pragma unroll
    for (int i = 0; i < 8; ++i) {
      int f = tid + 256 * i; int row = f >> 3, q = f & 7;
      float4 v = *(const float4*)(prop + (long)row * 256 + kc * 32 + 4 * q);
      float* p = lds + row * 33 + 4 * q;
      p[0] = v.x; p[1] = v.y; p[2] = v.z; p[3] = v.w;
    }
    __syncthreads();
    const float* wbase = cw1 + (long)r * CIN + 556 + kc * 32;
    const float* pl = lds + tid * 33;
#pragma unroll
    for (int k4 = 0; k4 < 8; ++k4) {
      float4 w4 = *(const float4*)(wbase + 4 * k4);
      const float* pp = pl + 4 * k4;
      acc += w4.x * pp[0] + w4.y * pp[1] + w4.z * pp[2] + w4.w * pp[3];
    }
  }
  ws[OFF_MPROP + (long)r * 256 + tid] = acc;
  // enc part: stage all of enc [50][256] -> lds [50][257]
  __syncthreads();
  for (int i = 0; i < 13; ++i) {
    int f = tid + 256 * i;
    if (f < 3200) {
      int row = f >> 6, q = f & 63;
      float4 v = *(const float4*)(enc + (long)row * 256 + 4 * q);
      float* p = lds + row * 257 + 4 * q;
      p[0] = v.x; p[1] = v.y; p[2] = v.z; p[3] = v.w;
    }
  }
  __syncthreads();
  if (tid < ML) {
    const float* wb2 = cw1 + (long)r * CIN + 300;
    const float* el = lds + tid * 257;
    float a2 = 0.f;
#pragma unroll 8
    for (int k = 0; k < 256; ++k) a2 += wb2[k] * el[k];
    ws[OFF_MENC + (long)r * ML + tid] = a2;
  }
}

// Persistent fused recurrence: 19 steps x 5 phases, device barrier between phases.
__global__ void __launch_bounds__(256) k_recur(
    const float* __restrict__ w1op, const float* __restrict__ w1l,
    const float* __restrict__ whh,  const float* __restrict__ bhh,
    const float* __restrict__ w2op, const float* __restrict__ b2op,
    const float* __restrict__ w2l,  const float* __restrict__ b2l,
    const int* __restrict__ obj_mask, const int* __restrict__ lang_mask,
    const float* __restrict__ wc2,  const float* __restrict__ bc2,
    const float* __restrict__ wih,  const float* __restrict__ bih,
    float* ws, float* __restrict__ out) {
  const int tid = threadIdx.x;
  const int lane = tid & 63;
  const int wv = (blockIdx.x << 2) + (tid >> 6);   // 0..511
  __shared__ float red[256];
  __shared__ __align__(16) float sm_aop[256];
  __shared__ float sm_al[64];

  for (int s = 0; s < T_STEPS; ++s) {
    // ---------- Phase A: h1op(256) | h1l(256) + gh(1536) ----------
    {
      const float* h = ws + OFF_HS + s * HDIM;
      float4 ha = *(const float4*)(h + 4 * lane);
      float4 hb = *(const float4*)(h + 256 + 4 * lane);
      const float* w0 = (wv < 256) ? (w1op + (long)wv * CIN + 300)
                                   : (w1l + (long)(wv - 256) * CIN + 300);
      const float* w1r = whh + (long)wv * HDIM;
      const float* w2r = whh + (long)(wv + 512) * HDIM;
      const float* w3r = whh + (long)(wv + 1024) * HDIM;
      float a0 = dot4(*(const float4*)(w0 + 4 * lane), ha) + dot4(*(const float4*)(w0 + 256 + 4 * lane), hb);
      float a1 = dot4(*(const float4*)(w1r + 4 * lane), ha) + dot4(*(const float4*)(w1r + 256 + 4 * lane), hb);
      float a2 = dot4(*(const float4*)(w2r + 4 * lane), ha) + dot4(*(const float4*)(w2r + 256 + 4 * lane), hb);
      float a3 = dot4(*(const float4*)(w3r + 4 * lane), ha) + dot4(*(const float4*)(w3r + 256 + 4 * lane), hb);
      a0 = wred(a0); a1 = wred(a1); a2 = wred(a2); a3 = wred(a3);
      if (lane == 0) {
        if (wv < 256) {
          float v = a0 + ws[OFF_POP + s * 256 + wv];
          ws[OFF_H1OP + wv] = v > 0.f ? v : 0.f;
        } else {
          float v = a0 + ws[OFF_PL + s * 256 + (wv - 256)];
          ws[OFF_H1L + (wv - 256)] = v > 0.f ? v : 0.f;
        }
        ws[OFF_GH + wv]        = a1 + bhh[wv];
        ws[OFF_GH + 512 + wv]  = a2 + bhh[512 + wv];
        ws[OFF_GH + 1024 + wv] = a3 + bhh[1024 + wv];
      }
    }
    gbar(ws);
    // ---------- Phase B: attention logits (306 rows) ----------
    if (wv < 306) {
      if (wv < 256) {
        float4 h1 = *(const float4*)(ws + OFF_H1OP + 4 * lane);
        const float* wr = w2op + (long)wv * 256;
        float acc = wred(dot4(*(const float4*)(wr + 4 * lane), h1));
        if (lane == 0) ws[OFF_LOGOP + wv] = acc + b2op[wv];
      } else {
        int r = wv - 256;
        float4 h1 = *(const float4*)(ws + OFF_H1L + 4 * lane);
        const float* wr = w2l + (long)r * 256;
        float acc = wred(dot4(*(const float4*)(wr + 4 * lane), h1));
        if (lane == 0) ws[OFF_LOGL + r] = acc + b2l[r];
      }
    }
    gbar(ws);
    // ---------- Phase C: block-redundant softmax + c1 ----------
    {
      float vo = (obj_mask[tid] != 0) ? NEGV : ws[OFF_LOGOP + tid];
      red[tid] = vo; __syncthreads();
      for (int st = 128; st > 0; st >>= 1) { if (tid < st) red[tid] = fmaxf(red[tid], red[tid + st]); __syncthreads(); }
      float mo = red[0]; __syncthreads();
      float eo = expf(vo - mo);
      red[tid] = eo; __syncthreads();
      for (int st = 128; st > 0; st >>= 1) { if (tid < st) red[tid] += red[tid + st]; __syncthreads(); }
      float aop = eo / red[0];
      sm_aop[tid] = aop;
      __syncthreads();
      float vl = (tid < ML) ? ((lang_mask[tid] != 0) ? NEGV : ws[OFF_LOGL + tid]) : -3e38f;
      red[tid] = vl; __syncthreads();
      for (int st = 128; st > 0; st >>= 1) { if (tid < st) red[tid] = fmaxf(red[tid], red[tid + st]); __syncthreads(); }
      float ml_ = red[0]; __syncthreads();
      float el = (tid < ML) ? expf(vl - ml_) : 0.f;
      red[tid] = el; __syncthreads();
      for (int st = 128; st > 0; st >>= 1) { if (tid < st) red[tid] += red[tid + st]; __syncthreads(); }
      float al = el / red[0];
      if (tid < 64) sm_al[tid] = (tid < ML) ? al : 0.f;
      __syncthreads();
      if (blockIdx.x == 0) {
        out[OUT_ATTOB + (long)s * NP + tid] = aop;
        if (tid < ML) out[OUT_ATTW + (long)s * ML + tid] = al;
      }
      // c1 row r = wv
      int r = wv;
      const float* mp = ws + OFF_MPROP + (long)r * 256;
      float4 m4 = *(const float4*)(mp + 4 * lane);
      float4 a4 = *(const float4*)(&sm_aop[4 * lane]);
      float acc = dot4(m4, a4);
      if (lane < ML) acc += ws[OFF_MENC + (long)r * ML + lane] * sm_al[lane];
      acc = wred(acc);
      if (lane == 0) {
        float v = acc + ws[OFF_PC + s * HDIM + r];
        ws[OFF_C1 + r] = v > 0.f ? v : 0.f;
      }
    }
    gbar(ws);
    // ---------- Phase D: g = relu(Wc2 @ c1 + b2) ----------
    {
      int r = wv;
      float4 ca = *(const float4*)(ws + OFF_C1 + 4 * lane);
      float4 cb = *(const float4*)(ws + OFF_C1 + 256 + 4 * lane);
      const float* wr = wc2 + (long)r * HDIM;
      float acc = wred(dot4(*(const float4*)(wr + 4 * lane), ca) + dot4(*(const float4*)(wr + 256 + 4 * lane), cb));
      if (lane == 0) {
        float v = acc + bc2[r];
        ws[OFF_G + r] = v > 0.f ? v : 0.f;
      }
    }
    gbar(ws);
    // ---------- Phase E: GRU fuse -> h_{s+1} ----------
    {
      int j = wv;
      float4 ga = *(const float4*)(ws + OFF_G + 4 * lane);
      float4 gb = *(const float4*)(ws + OFF_G + 256 + 4 * lane);
      const float* p0 = wih + (long)j * HDIM;
      const float* p1 = wih + (long)(j + 512) * HDIM;
      const float* p2 = wih + (long)(j + 1024) * HDIM;
      float a0 = dot4(*(const float4*)(p0 + 4 * lane), ga) + dot4(*(const float4*)(p0 + 256 + 4 * lane), gb);
      float a1 = dot4(*(const float4*)(p1 + 4 * lane), ga) + dot4(*(const float4*)(p1 + 256 + 4 * lane), gb);
      float a2 = dot4(*(const float4*)(p2 + 4 * lane), ga) + dot4(*(const float4*)(p2 + 256 + 4 * lane), gb);
      a0 = wred(a0); a1 = wred(a1); a2 = wred(a2);
      if (lane == 0) {
        float ir = a0 + bih[j], iz = a1 + bih[512 + j], in_ = a2 + bih[1024 + j];
        float hr = ws[OFF_GH + j], hz = ws[OFF_GH + 512 + j], hn = ws[OFF_GH + 1024 + j];
        float rg = 1.f / (1.f + expf(-(ir + hr)));
        float zg = 1.f / (1.f + expf(-(iz + hz)));
        float ng = tanhf(in_ + rg * hn);
        float hp = ws[OFF_HS + s * HDIM + j];
        ws[OFF_HS + (s + 1) * HDIM + j] = (1.f - zg) * ng + zg * hp;
      }
    }
    gbar(ws);
  }
}

// logits: LDS-tiled GEMM. 256 rows/block, k-chunks of 32, thread-owns-row.
__global__ void __launch_bounds__(256) k_final2(const float* __restrict__ ow,
                                                const float* __restrict__ ob,
                                                const float* __restrict__ ws,
                                                float* __restrict__ out) {
  __shared__ __align__(16) float wl[256 * 36];
  __shared__ __align__(16) float hl[T_STEPS * 512];
  int tid = threadIdx.x;
  long rbase = (long)blockIdx.x * 256;
  for (int i = tid; i < T_STEPS * 512; i += 256) hl[i] = ws[OFF_HS + 512 + i];
  float4 st[8];
  // prologue load chunk 0
#pragma unroll
  for (int i = 0; i < 8; ++i) {
    int f = tid + 256 * i; int row = f >> 3, q = f & 7;
    long r = rbase + row;
    st[i] = (r < V) ? *(const float4*)(ow + r * 512 + 4 * q) : make_float4(0.f, 0.f, 0.f, 0.f);
  }
  float acc[T_STEPS];
#pragma unroll
  for (int s = 0; s < T_STEPS; ++s) acc[s] = 0.f;
  __syncthreads();  // hl ready
  for (int c = 0; c < 16; ++c) {
    // write staged regs -> LDS
#pragma unroll
    for (int i = 0; i < 8; ++i) {
      int f = tid + 256 * i; int row = f >> 3, q = f & 7;
      float* p = wl + row * 36 + 4 * q;
      p[0] = st[i].x; p[1] = st[i].y; p[2] = st[i].z; p[3] = st[i].w;
    }
    __syncthreads();  // wl ready
    if (c < 15) {
#pragma unroll
      for (int i = 0; i < 8; ++i) {
        int f = tid + 256 * i; int row = f >> 3, q = f & 7;
        long r = rbase + row;
        st[i] = (r < V) ? *(const float4*)(ow + r * 512 + (c + 1) * 32 + 4 * q) : make_float4(0.f, 0.f, 0.f, 0.f);
      }
    }
    // compute: thread owns row=tid
    const float* wp = wl + tid * 36;
#pragma unroll
    for (int kq = 0; kq < 8; ++kq) {
      float4 w4 = *(const float4*)(wp + 4 * kq);
      const float* hb = hl + c * 32 + 4 * kq;
#pragma unroll
      for (int s = 0; s < T_STEPS; ++s) {
        float4 h4 = *(const float4*)(hb + s * 512);
        acc[s] += dot4(w4, h4);
      }
    }
    __syncthreads();  // done reading wl
  }
  long r = rbase + tid;
  if (r < V) {
    float b = ob[r];
#pragma unroll
    for (int s = 0; s < T_STEPS; ++s) out[OUT_LOGITS + (long)s * V + r] = acc[s] + b;
  }
}

extern "C" void kernel_launch(void* const* d_in, const int* in_sizes, int n_in,
                              void* d_out, int out_size, void* d_ws, size_t ws_size,
                              hipStream_t stream) {
  const int*   input_tok  = (const int*)d_in[0];
  const float* hidden     = (const float*)d_in[1];
  const float* enc        = (const float*)d_in[2];
  const float* prop       = (const float*)d_in[3];
  const int*   obj_mask   = (const int*)d_in[4];
  const int*   lang_mask  = (const int*)d_in[5];
  const int*   ans        = (const int*)d_in[6];
  const float* emb        = (const float*)d_in[7];
  const float* attn_w1    = (const float*)d_in[8];
  const float* attn_b1    = (const float*)d_in[9];
  const float* attn_w2    = (const float*)d_in[10];
  const float* attn_b2    = (const float*)d_in[11];
  const float* attn_op_w1 = (const float*)d_in[12];
  const float* attn_op_b1 = (const float*)d_in[13];
  const float* attn_op_w2 = (const float*)d_in[14];
  const float* attn_op_b2 = (const float*)d_in[15];
  const float* cmb_w1     = (const float*)d_in[16];
  const float* cmb_b1     = (const float*)d_in[17];
  const float* cmb_w2     = (const float*)d_in[18];
  const float* cmb_b2     = (const float*)d_in[19];
  const float* gw_ih      = (const float*)d_in[20];
  const float* gw_hh      = (const float*)d_in[21];
  const float* gb_ih      = (const float*)d_in[22];
  const float* gb_hh      = (const float*)d_in[23];
  const float* out_w      = (const float*)d_in[24];
  const float* out_b      = (const float*)d_in[25];
  float* out = (float*)d_out;
  float* ws  = (float*)d_ws;

  // reset barrier counters (root, gen, 16 leaves)
  hipMemsetAsync((char*)d_ws + (size_t)OFF_BAR * 4, 0, 4096, stream);
  k_pre1<<<25, 256, 0, stream>>>(input_tok, ans, emb, hidden, ws);
  k_pre2<<<4864, 256, 0, stream>>>(attn_op_w1, attn_op_b1, attn_w1, attn_b1, cmb_w1, cmb_b1, ws);
  k_mprep<<<512, 256, 0, stream>>>(cmb_w1, prop, enc, ws);
  k_recur<<<NBLK, 256, 0, stream>>>(attn_op_w1, attn_w1, gw_hh, gb_hh,
                                    attn_op_w2, attn_op_b2, attn_w2, attn_b2,
                                    obj_mask, lang_mask, cmb_w2, cmb_b2,
                                    gw_ih, gb_ih, ws, out);
  k_final2<<<(V + 255) / 256, 256, 0, stream>>>(out_w, out_b, ws, out);
}